// Round 8
// baseline (2192.180 us; speedup 1.0000x reference)
//
#include <hip/hip_runtime.h>
#include <hip/hip_bf16.h>

#define B_ROWS 131072
#define NSTEP  65
#define ROWS   64                   // rows per block
#define NBLK   (B_ROWS / ROWS)      // 2048 blocks -> 2 blocks/CU, lockstep weight stream
#define THREADS 512                 // 8 waves x 32 cols -> 4 waves/SIMD at 2 blocks/CU

typedef __attribute__((ext_vector_type(8))) short short8;
typedef __attribute__((ext_vector_type(4))) float floatx4;
typedef __attribute__((ext_vector_type(4))) unsigned int uintx4;

__device__ __forceinline__ unsigned short f2bf(float f) {
    unsigned int u = __builtin_bit_cast(unsigned int, f);
    u += 0x7FFFu + ((u >> 16) & 1u);   // RNE; inputs are finite
    return (unsigned short)(u >> 16);
}

// native pack: compiler emits v_cvt_pk_bf16_f32 (RNE, same bits as f2bf pair)
__device__ __forceinline__ unsigned pack_bf16(float lo, float hi) {
    unsigned short l = __bfloat16_as_ushort(__float2bfloat16(lo));
    unsigned short h = __bfloat16_as_ushort(__float2bfloat16(hi));
    return (unsigned)l | ((unsigned)h << 16);
}

// ---- pack W1 (65,63,256) fp32 -> bf16 frag order [stp][kc<2][n<256][32 k]
// k=63 row carries b1 (bias folded; z-tile col 63 is pinned to 1.0)
__global__ __launch_bounds__(256) void pack_w1(const float* __restrict__ W1,
                                               const float* __restrict__ b1,
                                               unsigned short* __restrict__ out) {
    int t = blockIdx.x * 256 + threadIdx.x;            // 65*2*256 = 33280 threads
    int n = t & 255, kc = (t >> 8) & 1, stp = t >> 9;
    unsigned int wbuf[16];
#pragma unroll
    for (int e = 0; e < 16; ++e) {
        int k0 = kc * 32 + e * 2, k1 = k0 + 1;
        float v0 = (k0 < 63) ? W1[((size_t)stp * 63 + k0) * 256 + n] : b1[(size_t)stp * 256 + n];
        float v1 = (k1 < 63) ? W1[((size_t)stp * 63 + k1) * 256 + n] : b1[(size_t)stp * 256 + n];
        wbuf[e] = (unsigned)f2bf(v0) | ((unsigned)f2bf(v1) << 16);
    }
    uintx4* o = (uintx4*)out;
#pragma unroll
    for (int j = 0; j < 4; ++j) {
        uintx4 u = {wbuf[j*4+0], wbuf[j*4+1], wbuf[j*4+2], wbuf[j*4+3]};
        o[(size_t)t * 4 + j] = u;
    }
}

// ---- pack W2 (65,256,256) fp32 -> bf16 frag order [stp][kc<8][n<256][32 k]
__global__ __launch_bounds__(256) void pack_w2(const float* __restrict__ W2,
                                               unsigned short* __restrict__ out) {
    int t = blockIdx.x * 256 + threadIdx.x;            // 65*8*256 = 133120 threads
    int n = t & 255, kc = (t >> 8) & 7, stp = t >> 11;
    unsigned int wbuf[16];
#pragma unroll
    for (int e = 0; e < 16; ++e) {
        int k0 = kc * 32 + e * 2;
        float v0 = W2[((size_t)stp * 256 + k0) * 256 + n];
        float v1 = W2[((size_t)stp * 256 + k0 + 1) * 256 + n];
        wbuf[e] = (unsigned)f2bf(v0) | ((unsigned)f2bf(v1) << 16);
    }
    uintx4* o = (uintx4*)out;
#pragma unroll
    for (int j = 0; j < 4; ++j) {
        uintx4 u = {wbuf[j*4+0], wbuf[j*4+1], wbuf[j*4+2], wbuf[j*4+3]};
        o[(size_t)t * 4 + j] = u;
    }
}

// ---- whole 65-step flow; block owns 64 rows, z resident in LDS, 2 blocks/CU.
// 8 waves x 32 output-cols; 2 barriers/step (redundant per-wave tail).
// amdgpu_waves_per_eu(4,4): occupancy is LDS-capped at 4 waves/EU anyway, so
// let the allocator use the full 128-VGPR budget (round-6 spilled at a
// self-imposed 64-VGPR cap).
// Transposed-MFMA: A = weights (global frag-packed), B = activations (LDS).
// C-layout: lane holds col1 = i4*16+q*4+r, row = j*16+c.
__global__ void
__attribute__((amdgpu_flat_work_group_size(THREADS, THREADS)))
__attribute__((amdgpu_waves_per_eu(4, 4)))
flow_kernel(
    const float* __restrict__ x,
    const float* __restrict__ sg,
    const unsigned short* __restrict__ Wb1p,
    const unsigned short* __restrict__ Wb2p,
    const float* __restrict__ b2g,
    const float* __restrict__ w3g,
    const float* __restrict__ b3g,
    const int* __restrict__ idxg,
    float* __restrict__ out)
{
    __shared__ float  zm[ROWS][65];      // fp32 master z                        16,640 B
    __shared__ uintx4 tileA[ROWS * 8];   // bf16 z tile, 8x16B chunks/row, swz    8,192 B
    __shared__ uintx4 H1[ROWS * 32];     // bf16 h1, 32x16B chunks/row, swz      32,768 B
    __shared__ float  TR[8][ROWS];       // per-wave partial t                    2,048 B

    const int tid  = threadIdx.x;
    const int w    = tid >> 6;           // wave 0..7 owns cols [w*32, w*32+32)
    const int lane = tid & 63;
    const int q    = lane >> 4;
    const int c    = lane & 15;
    const int b0   = blockIdx.x * ROWS;

    unsigned short*     tileS = (unsigned short*)tileA;
    unsigned long long* H1u   = (unsigned long long*)H1;
    const uintx4* w1v = (const uintx4*)Wb1p;
    const uintx4* w2v = (const uintx4*)Wb2p;

    // ---- init: coalesced x load -> zm (fp32) + tileA (bf16, swizzled); col 63 = 1.0 (bias lane)
#pragma unroll 4
    for (int it = 0; it < (ROWS * 64) / THREADS; ++it) {   // 8 iters
        int flat = it * THREADS + tid;
        int row = flat >> 6, col = flat & 63;
        float v = x[(size_t)(b0 + row) * 64 + col];
        zm[row][col] = v;
        tileS[row * 64 + ((((col >> 3) ^ (row & 7)) << 3) | (col & 7))] =
            (col == 63) ? (unsigned short)0x3F80u : f2bf(v);
    }
    __syncthreads();

    // prologue fixup for step 0: tile slot idx[0] shows old column 63
    if (tid < ROWS) {
        int row = tid, i0 = idxg[0];
        tileS[row * 64 + ((((i0 >> 3) ^ (row & 7)) << 3) | (i0 & 7))] = f2bf(zm[row][63]);
    }
    __syncthreads();

    // preload W1 fragments for step 0 (16 VGPR, budget-safe under waves_per_eu(4,4))
    short8 aw1[2][2];                    // [kc][i4]
#pragma unroll
    for (int kc = 0; kc < 2; ++kc)
#pragma unroll
        for (int i4 = 0; i4 < 2; ++i4)
            aw1[kc][i4] = __builtin_bit_cast(short8,
                w1v[((size_t)kc * 256 + w * 32 + i4 * 16 + c) * 4 + q]);

#pragma unroll 1
    for (int step = 0; step < NSTEP; ++step) {
        const int i   = idxg[step];
        const int inx = (step + 1 < NSTEP) ? idxg[step + 1] : 0;
        const float b3v = b3g[step];

        floatx4 acc[2][4];
#pragma unroll
        for (int a = 0; a < 2; ++a)
#pragma unroll
            for (int b = 0; b < 4; ++b) acc[a][b] = (floatx4){0.f, 0.f, 0.f, 0.f};

        // ---- phase 1: h1^T = W1^T @ z^T   (K = 64, b1 folded into k=63)
#pragma unroll
        for (int kc = 0; kc < 2; ++kc) {
            short8 bz[4];
#pragma unroll
            for (int j = 0; j < 4; ++j)
                bz[j] = __builtin_bit_cast(short8,
                    tileA[(j * 16 + c) * 8 + ((kc * 4 + q) ^ (c & 7))]);
#pragma unroll
            for (int i4 = 0; i4 < 2; ++i4)
#pragma unroll
                for (int j = 0; j < 4; ++j)
                    acc[i4][j] = __builtin_amdgcn_mfma_f32_16x16x32_bf16(
                        aw1[kc][i4], bz[j], acc[i4][j], 0, 0, 0);
        }

        // prefetch next step's W1 fragments (L2 latency hidden under epi-1 + phase 2)
        if (step + 1 < NSTEP) {
#pragma unroll
            for (int kc = 0; kc < 2; ++kc)
#pragma unroll
                for (int i4 = 0; i4 < 2; ++i4)
                    aw1[kc][i4] = __builtin_bit_cast(short8,
                        w1v[((size_t)((step + 1) * 2 + kc) * 256 + w * 32 + i4 * 16 + c) * 4 + q]);
        }

        // ---- epi-1: relu -> H1 bf16 via native cvt_pk (bias already in acc)
#pragma unroll
        for (int i4 = 0; i4 < 2; ++i4) {
            int c16 = (w * 4 + i4 * 2 + (q >> 1)) ^ c;   // swizzle mask = row&15 = c
#pragma unroll
            for (int j = 0; j < 4; ++j) {
                int row = j * 16 + c;
                unsigned d0 = pack_bf16(fmaxf(acc[i4][j][0], 0.f),
                                        fmaxf(acc[i4][j][1], 0.f));
                unsigned d1 = pack_bf16(fmaxf(acc[i4][j][2], 0.f),
                                        fmaxf(acc[i4][j][3], 0.f));
                H1u[(row * 32 + c16) * 2 + (q & 1)] =
                    (unsigned long long)d0 | ((unsigned long long)d1 << 32);
            }
        }
        __syncthreads();   // barrier #1: H1 complete

        // ---- phase 2: h2^T = W2^T @ h1^T   (K = 256)
#pragma unroll
        for (int a = 0; a < 2; ++a)
#pragma unroll
            for (int b = 0; b < 4; ++b) acc[a][b] = (floatx4){0.f, 0.f, 0.f, 0.f};

#pragma unroll
        for (int kc = 0; kc < 8; ++kc) {
            short8 bh[4], aw[2];
#pragma unroll
            for (int j = 0; j < 4; ++j)
                bh[j] = __builtin_bit_cast(short8,
                    H1[(j * 16 + c) * 32 + ((kc * 4 + q) ^ c)]);
#pragma unroll
            for (int i4 = 0; i4 < 2; ++i4)
                aw[i4] = __builtin_bit_cast(short8,
                    w2v[((size_t)(step * 8 + kc) * 256 + w * 32 + i4 * 16 + c) * 4 + q]);
#pragma unroll
            for (int i4 = 0; i4 < 2; ++i4)
#pragma unroll
                for (int j = 0; j < 4; ++j)
                    acc[i4][j] = __builtin_amdgcn_mfma_f32_16x16x32_bf16(
                        aw[i4], bh[j], acc[i4][j], 0, 0, 0);
        }

        // ---- epi-2: t = relu(h2 + b2) . w3 (32 cols in-register; 2 shuffles)
        {
            float p[4];
#pragma unroll
            for (int j = 0; j < 4; ++j) p[j] = 0.f;
#pragma unroll
            for (int i4 = 0; i4 < 2; ++i4) {
#pragma unroll
                for (int r = 0; r < 4; ++r) {
                    int col2 = step * 256 + w * 32 + i4 * 16 + q * 4 + r;
                    float bb = b2g[col2];
                    float ww = w3g[col2];
#pragma unroll
                    for (int j = 0; j < 4; ++j)
                        p[j] += fmaxf(acc[i4][j][r] + bb, 0.f) * ww;
                }
            }
#pragma unroll
            for (int j = 0; j < 4; ++j) {
                float t = p[j];
                t += __shfl_xor(t, 16, 64);
                t += __shfl_xor(t, 32, 64);
                if (q == 0) TR[w][j * 16 + c] = t;
            }
        }

        // pre-read z values needed by the tail (before barrier #2; last zm write
        // was wave 0's tail at step-1, ordered by this step's barrier #1)
        float zold = zm[lane][i];
        float z63  = zm[lane][63];
        __syncthreads();   // barrier #2: TR complete

        // ---- redundant per-wave tail: every wave computes the identical update
        // (bit-identical TR sum + zold), so concurrent same-value tile writes are
        // benign and each wave's next phase-1 reads its OWN writes -> no barrier.
        // Only wave 0 writes fp32 zm. Slot 63 = pinned 1.0 bias lane.
        {
            int row = lane;
            float t = TR[0][row] + TR[1][row] + TR[2][row] + TR[3][row]
                    + TR[4][row] + TR[5][row] + TR[6][row] + TR[7][row] + b3v;
            float nz = zold + t;
            if (w == 0) zm[row][i] = nz;
            if (i != 63)
                tileS[row * 64 + ((((i >> 3) ^ (row & 7)) << 3) | (i & 7))] = f2bf(nz);
            if (step + 1 < NSTEP) {
                float z63v = (i == 63) ? nz : z63;
                if (inx != 63)
                    tileS[row * 64 + ((((inx >> 3) ^ (row & 7)) << 3) | (inx & 7))] =
                        f2bf(z63v);
            }
        }
        // no barrier #3: H1/TR/zm hazards are ordered by barriers #1/#2 of the
        // next iteration (verified correct in round 6).
    }

    __syncthreads();   // all tails done before TR is repurposed
    // ---- finalize: out[b][j] = exp(s[j]) * zm  (coalesced)
    if (tid < 64) ((float*)TR)[tid] = expf(sg[tid]);
    __syncthreads();
#pragma unroll 4
    for (int it = 0; it < (ROWS * 64) / THREADS; ++it) {
        int flat = it * THREADS + tid;
        int row = flat >> 6, col = flat & 63;
        out[(size_t)(b0 + row) * 64 + col] = ((float*)TR)[col] * zm[row][col];
    }
}

extern "C" void kernel_launch(void* const* d_in, const int* in_sizes, int n_in,
                              void* d_out, int out_size, void* d_ws, size_t ws_size,
                              hipStream_t stream) {
    const float* x  = (const float*)d_in[0];
    const float* s  = (const float*)d_in[1];
    const float* W1 = (const float*)d_in[2];
    const float* b1 = (const float*)d_in[3];
    const float* W2 = (const float*)d_in[4];
    const float* b2 = (const float*)d_in[5];
    const float* W3 = (const float*)d_in[6];
    const float* b3 = (const float*)d_in[7];
    const int* idx  = (const int*)d_in[8];
    float* out = (float*)d_out;

    char* ws = (char*)d_ws;
    const size_t W1P_BYTES = (size_t)NSTEP * 2 * 256 * 32 * 2;   //  2,129,920
    unsigned short* Wb1p = (unsigned short*)ws;
    unsigned short* Wb2p = (unsigned short*)(ws + W1P_BYTES);

    pack_w1<<<130, 256, 0, stream>>>(W1, b1, Wb1p);
    pack_w2<<<520, 256, 0, stream>>>(W2, Wb2p);
    flow_kernel<<<NBLK, THREADS, 0, stream>>>(x, s, Wb1p, Wb2p, b2, W3, b3, idx, out);
}

// Round 9
// 1788.278 us; speedup vs baseline: 1.2259x; 1.2259x over previous
//
#include <hip/hip_runtime.h>
#include <hip/hip_bf16.h>

#define B_ROWS 131072
#define NSTEP  65
#define ROWS   64                   // rows per block
#define NBLK   (B_ROWS / ROWS)      // 2048 blocks -> 2 blocks/CU, lockstep weight stream
#define THREADS 512                 // 8 waves x 32 cols -> 4 waves/SIMD at 2 blocks/CU

typedef __attribute__((ext_vector_type(8))) short short8;
typedef __attribute__((ext_vector_type(4))) float floatx4;
typedef __attribute__((ext_vector_type(4))) unsigned int uintx4;

#define W1_SLICE 32768u             // bytes per step in packed W1
#define W2_SLICE 131072u            // bytes per step in packed W2
#define SLICE_TOT (W1_SLICE + W2_SLICE)   // 163840

__device__ __forceinline__ unsigned short f2bf(float f) {
    unsigned int u = __builtin_bit_cast(unsigned int, f);
    u += 0x7FFFu + ((u >> 16) & 1u);   // RNE; inputs are finite
    return (unsigned short)(u >> 16);
}

// native pack: compiler emits v_cvt_pk_bf16_f32 (RNE, same bits as f2bf pair)
__device__ __forceinline__ unsigned pack_bf16(float lo, float hi) {
    unsigned short l = __bfloat16_as_ushort(__float2bfloat16(lo));
    unsigned short h = __bfloat16_as_ushort(__float2bfloat16(hi));
    return (unsigned)l | ((unsigned)h << 16);
}

// ---- pack W1 (65,63,256) fp32 -> bf16 frag order [stp][kc<2][n<256][32 k]
// k=63 row carries b1 (bias folded; z-tile col 63 is pinned to 1.0)
__global__ __launch_bounds__(256) void pack_w1(const float* __restrict__ W1,
                                               const float* __restrict__ b1,
                                               unsigned short* __restrict__ out) {
    int t = blockIdx.x * 256 + threadIdx.x;            // 65*2*256 = 33280 threads
    int n = t & 255, kc = (t >> 8) & 1, stp = t >> 9;
    unsigned int wbuf[16];
#pragma unroll
    for (int e = 0; e < 16; ++e) {
        int k0 = kc * 32 + e * 2, k1 = k0 + 1;
        float v0 = (k0 < 63) ? W1[((size_t)stp * 63 + k0) * 256 + n] : b1[(size_t)stp * 256 + n];
        float v1 = (k1 < 63) ? W1[((size_t)stp * 63 + k1) * 256 + n] : b1[(size_t)stp * 256 + n];
        wbuf[e] = (unsigned)f2bf(v0) | ((unsigned)f2bf(v1) << 16);
    }
    uintx4* o = (uintx4*)out;
#pragma unroll
    for (int j = 0; j < 4; ++j) {
        uintx4 u = {wbuf[j*4+0], wbuf[j*4+1], wbuf[j*4+2], wbuf[j*4+3]};
        o[(size_t)t * 4 + j] = u;
    }
}

// ---- pack W2 (65,256,256) fp32 -> bf16 frag order [stp][kc<8][n<256][32 k]
__global__ __launch_bounds__(256) void pack_w2(const float* __restrict__ W2,
                                               unsigned short* __restrict__ out) {
    int t = blockIdx.x * 256 + threadIdx.x;            // 65*8*256 = 133120 threads
    int n = t & 255, kc = (t >> 8) & 7, stp = t >> 11;
    unsigned int wbuf[16];
#pragma unroll
    for (int e = 0; e < 16; ++e) {
        int k0 = kc * 32 + e * 2;
        float v0 = W2[((size_t)stp * 256 + k0) * 256 + n];
        float v1 = W2[((size_t)stp * 256 + k0 + 1) * 256 + n];
        wbuf[e] = (unsigned)f2bf(v0) | ((unsigned)f2bf(v1) << 16);
    }
    uintx4* o = (uintx4*)out;
#pragma unroll
    for (int j = 0; j < 4; ++j) {
        uintx4 u = {wbuf[j*4+0], wbuf[j*4+1], wbuf[j*4+2], wbuf[j*4+3]};
        o[(size_t)t * 4 + j] = u;
    }
}

// ---- whole 65-step flow; block owns 64 rows, z resident in LDS, 2 blocks/CU.
// 8 waves x 32 output-cols each (4 waves/SIMD across 2 independent blocks).
// L2-warm prefetch: each thread touches 16B of step s+1's weight slice per
// step (dead read, kept alive via empty asm) so phase-2 loads hit L2.
// Transposed-MFMA: A = weights (global frag-packed), B = activations (LDS).
// C-layout: lane holds col1 = i4*16+q*4+r, row = j*16+c.
__global__ __launch_bounds__(THREADS, 4) void flow_kernel(
    const float* __restrict__ x,
    const float* __restrict__ sg,
    const unsigned short* __restrict__ Wb1p,
    const unsigned short* __restrict__ Wb2p,
    const float* __restrict__ b2g,
    const float* __restrict__ w3g,
    const float* __restrict__ b3g,
    const int* __restrict__ idxg,
    float* __restrict__ out)
{
    __shared__ float  zm[ROWS][65];      // fp32 master z                        16,640 B
    __shared__ uintx4 tileA[ROWS * 8];   // bf16 z tile, 8x16B chunks/row, swz    8,192 B
    __shared__ uintx4 H1[ROWS * 32];     // bf16 h1, 32x16B chunks/row, swz      32,768 B
    __shared__ float  TR[8][ROWS];       // per-wave partial t                    2,048 B

    const int tid  = threadIdx.x;
    const int w    = tid >> 6;           // wave 0..7 owns cols [w*32, w*32+32)
    const int lane = tid & 63;
    const int q    = lane >> 4;
    const int c    = lane & 15;
    const int b0   = blockIdx.x * ROWS;

    unsigned short*     tileS = (unsigned short*)tileA;
    unsigned long long* H1u   = (unsigned long long*)H1;
    const uintx4* w1v = (const uintx4*)Wb1p;
    const uintx4* w2v = (const uintx4*)Wb2p;

    // per-thread L2-warm offset within a step's 160KB virtual weight slice.
    // kb = block index within XCD cohort (blockIdx>>3); stripe walk has
    // period 20 in kb, so any >=20 co-resident blocks/XCD cover the slice.
    const unsigned pfOff = ((unsigned)((blockIdx.x >> 3) * THREADS + tid) * 16u) % SLICE_TOT;

    // ---- init: coalesced x load -> zm (fp32) + tileA (bf16, swizzled); col 63 = 1.0 (bias lane)
#pragma unroll 4
    for (int it = 0; it < (ROWS * 64) / THREADS; ++it) {   // 8 iters
        int flat = it * THREADS + tid;
        int row = flat >> 6, col = flat & 63;
        float v = x[(size_t)(b0 + row) * 64 + col];
        zm[row][col] = v;
        tileS[row * 64 + ((((col >> 3) ^ (row & 7)) << 3) | (col & 7))] =
            (col == 63) ? (unsigned short)0x3F80u : f2bf(v);
    }
    __syncthreads();

    // prologue fixup for step 0: tile slot idx[0] shows old column 63
    if (tid < ROWS) {
        int row = tid, i0 = idxg[0];
        tileS[row * 64 + ((((i0 >> 3) ^ (row & 7)) << 3) | (i0 & 7))] = f2bf(zm[row][63]);
    }
    __syncthreads();

#pragma unroll 1
    for (int step = 0; step < NSTEP; ++step) {
        const int i = idxg[step];

        // ---- L2-warm prefetch of step s+1's weight slice (dead 16B read).
        // Transient registers only; result consumed by empty asm (rule #17).
        if (step + 1 < NSTEP) {
            const char* src = (pfOff < W1_SLICE)
                ? (const char*)Wb1p + (size_t)(step + 1) * W1_SLICE + pfOff
                : (const char*)Wb2p + (size_t)(step + 1) * W2_SLICE + (pfOff - W1_SLICE);
            uintx4 junk = *(const uintx4*)src;
            asm volatile("" :: "v"(junk));
        }

        floatx4 acc[2][4];
#pragma unroll
        for (int a = 0; a < 2; ++a)
#pragma unroll
            for (int b = 0; b < 4; ++b) acc[a][b] = (floatx4){0.f, 0.f, 0.f, 0.f};

        // ---- phase 1: h1^T = W1^T @ z^T   (K = 64, b1 folded into k=63)
#pragma unroll
        for (int kc = 0; kc < 2; ++kc) {
            short8 bz[4], aw[2];
#pragma unroll
            for (int j = 0; j < 4; ++j)
                bz[j] = __builtin_bit_cast(short8,
                    tileA[(j * 16 + c) * 8 + ((kc * 4 + q) ^ (c & 7))]);
#pragma unroll
            for (int i4 = 0; i4 < 2; ++i4)
                aw[i4] = __builtin_bit_cast(short8,
                    w1v[((size_t)(step * 2 + kc) * 256 + w * 32 + i4 * 16 + c) * 4 + q]);
#pragma unroll
            for (int i4 = 0; i4 < 2; ++i4)
#pragma unroll
                for (int j = 0; j < 4; ++j)
                    acc[i4][j] = __builtin_amdgcn_mfma_f32_16x16x32_bf16(
                        aw[i4], bz[j], acc[i4][j], 0, 0, 0);
        }

        // ---- epi-1: relu -> H1 bf16 via native cvt_pk (bias already in acc)
#pragma unroll
        for (int i4 = 0; i4 < 2; ++i4) {
            int c16 = (w * 4 + i4 * 2 + (q >> 1)) ^ c;   // swizzle mask = row&15 = c
#pragma unroll
            for (int j = 0; j < 4; ++j) {
                int row = j * 16 + c;
                unsigned d0 = pack_bf16(fmaxf(acc[i4][j][0], 0.f),
                                        fmaxf(acc[i4][j][1], 0.f));
                unsigned d1 = pack_bf16(fmaxf(acc[i4][j][2], 0.f),
                                        fmaxf(acc[i4][j][3], 0.f));
                H1u[(row * 32 + c16) * 2 + (q & 1)] =
                    (unsigned long long)d0 | ((unsigned long long)d1 << 32);
            }
        }
        __syncthreads();

        // ---- phase 2: h2^T = W2^T @ h1^T   (K = 256)
#pragma unroll
        for (int a = 0; a < 2; ++a)
#pragma unroll
            for (int b = 0; b < 4; ++b) acc[a][b] = (floatx4){0.f, 0.f, 0.f, 0.f};

#pragma unroll
        for (int kc = 0; kc < 8; ++kc) {
            short8 bh[4], aw[2];
#pragma unroll
            for (int j = 0; j < 4; ++j)
                bh[j] = __builtin_bit_cast(short8,
                    H1[(j * 16 + c) * 32 + ((kc * 4 + q) ^ c)]);
#pragma unroll
            for (int i4 = 0; i4 < 2; ++i4)
                aw[i4] = __builtin_bit_cast(short8,
                    w2v[((size_t)(step * 8 + kc) * 256 + w * 32 + i4 * 16 + c) * 4 + q]);
#pragma unroll
            for (int i4 = 0; i4 < 2; ++i4)
#pragma unroll
                for (int j = 0; j < 4; ++j)
                    acc[i4][j] = __builtin_amdgcn_mfma_f32_16x16x32_bf16(
                        aw[i4], bh[j], acc[i4][j], 0, 0, 0);
        }

        // ---- epi-2: t = relu(h2 + b2) . w3 (32 cols in-register; 2 shuffles)
        {
            float p[4];
#pragma unroll
            for (int j = 0; j < 4; ++j) p[j] = 0.f;
#pragma unroll
            for (int i4 = 0; i4 < 2; ++i4) {
#pragma unroll
                for (int r = 0; r < 4; ++r) {
                    int col2 = step * 256 + w * 32 + i4 * 16 + q * 4 + r;
                    float bb = b2g[col2];
                    float ww = w3g[col2];
#pragma unroll
                    for (int j = 0; j < 4; ++j)
                        p[j] += fmaxf(acc[i4][j][r] + bb, 0.f) * ww;
                }
            }
#pragma unroll
            for (int j = 0; j < 4; ++j) {
                float t = p[j];
                t += __shfl_xor(t, 16, 64);
                t += __shfl_xor(t, 32, 64);
                if (q == 0) TR[w][j * 16 + c] = t;
            }
        }
        __syncthreads();

        // ---- update zm[row][i] += t, refresh tile slot i; then fixup for next step.
        // Slot 63 is the pinned 1.0 bias lane: never overwrite it (i==63 only at step 63).
        if (tid < ROWS) {
            int row = tid;
            float t = TR[0][row] + TR[1][row] + TR[2][row] + TR[3][row]
                    + TR[4][row] + TR[5][row] + TR[6][row] + TR[7][row] + b3g[step];
            float nz = zm[row][i] + t;
            zm[row][i] = nz;
            if (i != 63)
                tileS[row * 64 + ((((i >> 3) ^ (row & 7)) << 3) | (i & 7))] = f2bf(nz);
            if (step + 1 < NSTEP) {
                int in = idxg[step + 1];
                if (in != 63)
                    tileS[row * 64 + ((((in >> 3) ^ (row & 7)) << 3) | (in & 7))] =
                        f2bf(zm[row][63]);
            }
        }
        __syncthreads();
    }

    // ---- finalize: out[b][j] = exp(s[j]) * zm  (coalesced)
    if (tid < 64) ((float*)TR)[tid] = expf(sg[tid]);
    __syncthreads();
#pragma unroll 4
    for (int it = 0; it < (ROWS * 64) / THREADS; ++it) {
        int flat = it * THREADS + tid;
        int row = flat >> 6, col = flat & 63;
        out[(size_t)(b0 + row) * 64 + col] = ((float*)TR)[col] * zm[row][col];
    }
}

extern "C" void kernel_launch(void* const* d_in, const int* in_sizes, int n_in,
                              void* d_out, int out_size, void* d_ws, size_t ws_size,
                              hipStream_t stream) {
    const float* x  = (const float*)d_in[0];
    const float* s  = (const float*)d_in[1];
    const float* W1 = (const float*)d_in[2];
    const float* b1 = (const float*)d_in[3];
    const float* W2 = (const float*)d_in[4];
    const float* b2 = (const float*)d_in[5];
    const float* W3 = (const float*)d_in[6];
    const float* b3 = (const float*)d_in[7];
    const int* idx  = (const int*)d_in[8];
    float* out = (float*)d_out;

    char* ws = (char*)d_ws;
    const size_t W1P_BYTES = (size_t)NSTEP * 2 * 256 * 32 * 2;   //  2,129,920
    unsigned short* Wb1p = (unsigned short*)ws;
    unsigned short* Wb2p = (unsigned short*)(ws + W1P_BYTES);

    pack_w1<<<130, 256, 0, stream>>>(W1, b1, Wb1p);
    pack_w2<<<520, 256, 0, stream>>>(W2, Wb2p);
    flow_kernel<<<NBLK, THREADS, 0, stream>>>(x, s, Wb1p, Wb2p, b2, W3, b3, idx, out);
}